// Round 4
// baseline (6653.854 us; speedup 1.0000x reference)
//
#include <hip/hip_runtime.h>

// ResidualSkipRNNForecaster — R10: sentinel-payload rendezvous (1 round trip),
// zero flags, 2 barriers/slot.
//
// R9 post-mortem: 3.05us/slot; VALU 0.47us + MFMA 0.17us -> ~2.4us is
// rendezvous latency: publish -> b2 drain -> flag store -> flag one-way ->
// poll -> SECOND round trip loading payload. R10:
//   1. Payload words are sentinel-initialized (0xFFFF.. = 4x bf16-NaN /
//      (-NaN,-NaN) — unreachable by real data) and replicated x16 (one
//      private copy per reader; 8B atomic stores, tear-free). Readers poll
//      their private copy directly: ONE one-way latency. After consuming,
//      reader re-sentinels its copy (private => no multi-reader clash).
//   2. Flags DELETED. Writer safety (parity-par reuse at slot s vs readers
//      of slot s-2) is implied: epilogue(s) follows b3(s-1) => we observed
//      every peer's slot-(s-1) payload => peer passed b1(s-1) => passed
//      b3(s-2) => its re-sentinel stores of parity-par were vmcnt-drained
//      (applied at the coherence point) before the payload we observed was
//      issued. So our overwrite cannot precede their re-sentinel.
//   3. b2 deleted (only remaining role was drain-before-flag): 2 barriers
//      per slot (b1: MFMA->epilogue; b3: gather/LDS-writes -> next slot).
//      Own LN-stats written directly in epilogue (all st0/st1 reads are
//      hoisted before b1).
//   4. Head: own block's contribution from LDS (a1bf/st1), peers via
//      sentinel-poll (self-slot words are never re-sentineled, so LDS is
//      the only stale-proof source for own data).
// ws: cvec 16KB | pay 8MB | pst 1MB  (~9.5MB total; prep fills sentinel).

#define T_SZ 1024
#define DD   64
#define HH   512
#define NCH  8
#define NBLK 16
#define SENT 0xFFFFFFFFFFFFFFFFull

typedef __attribute__((ext_vector_type(8))) short short8;
typedef __attribute__((ext_vector_type(4))) float f32x4;
typedef unsigned long long ull;

__device__ __forceinline__ unsigned short f2b(float f) {
  unsigned u = __float_as_uint(f);
  u += 0x7fffu + ((u >> 16) & 1u);   // RNE
  return (unsigned short)(u >> 16);
}
__device__ __forceinline__ float b2f(unsigned short s) {
  return __uint_as_float(((unsigned)s) << 16);
}
__device__ __forceinline__ ull packf2(float a, float b) {
  return (ull)__float_as_uint(a) | ((ull)__float_as_uint(b) << 32);
}
__device__ __forceinline__ float unpack_lo(ull u) { return __uint_as_float((unsigned)u); }
__device__ __forceinline__ float unpack_hi(ull u) { return __uint_as_float((unsigned)(u >> 32)); }
__device__ __forceinline__ void st_rlx(ull* p, ull v) {
  __hip_atomic_store(p, v, __ATOMIC_RELAXED, __HIP_MEMORY_SCOPE_AGENT);
}
__device__ __forceinline__ ull ld_rlx(const ull* p) {
  return __hip_atomic_load(p, __ATOMIC_RELAXED, __HIP_MEMORY_SCOPE_AGENT);
}
// tanh(z) = 1 - 2/(e^{2z}+1), exact; exp2+rcp HW approx (~1e-7 abs err).
__device__ __forceinline__ float fast_tanh(float z) {
  const float e = __builtin_amdgcn_exp2f(z * 2.885390081777927f);  // e^{2z}
  return 1.f - 2.f * __builtin_amdgcn_rcpf(e + 1.f);
}

__global__ void prep_kernel(const float* __restrict__ Wh0, const float* __restrict__ Wi1,
                            const float* __restrict__ Wh1,
                            const float* __restrict__ bi0, const float* __restrict__ bh0,
                            const float* __restrict__ bi1, const float* __restrict__ bh1,
                            const float* __restrict__ g0, const float* __restrict__ be0,
                            const float* __restrict__ g1, const float* __restrict__ be1,
                            float* __restrict__ cvec,
                            ull* __restrict__ pay, ull* __restrict__ pst) {
  int g = blockIdx.x * blockDim.x + threadIdx.x;
  if (g < HH) {
    float uw0 = 0.f, qw0 = 0.f, uw1 = 0.f, qw1 = 0.f, uh1 = 0.f, qh1 = 0.f;
    for (int j = 0; j < HH; ++j) {
      float a = Wh0[j * HH + g], b = Wi1[j * HH + g], d = Wh1[j * HH + g];
      uw0 += g0[j] * a; qw0 += be0[j] * a;
      uw1 += g0[j] * b; qw1 += be0[j] * b;
      uh1 += g1[j] * d; qh1 += be1[j] * d;
    }
    float b0 = bi0[g] + bh0[g], b1 = bi1[g] + bh1[g];
    cvec[0 * HH + g] = b0 + qw0;        // c0 full (t>0)
    cvec[1 * HH + g] = b0;              // c0 init (t==0)
    cvec[2 * HH + g] = b1 + qw1 + qh1;  // c1 full
    cvec[3 * HH + g] = b1 + qw1;        // c1 init
    cvec[4 * HH + g] = uw0;
    cvec[5 * HH + g] = uw1;
    cvec[6 * HH + g] = uh1;
  }
  // sentinel fill: pay = 1,048,576 words, pst = 131,072 words; 65536 threads
  ull* pp = pay + (size_t)g * 16;
#pragma unroll
  for (int i = 0; i < 16; ++i) pp[i] = SENT;
  ull* ps = pst + (size_t)g * 2;
#pragma unroll
  for (int i = 0; i < 2; ++i) ps[i] = SENT;
}

__global__ __launch_bounds__(512, 1) void rnn_mfma(
    const float* __restrict__ x,
    const float* __restrict__ Wi0, const float* __restrict__ Wh0,
    const float* __restrict__ Wi1, const float* __restrict__ Wh1,
    const float* __restrict__ cvec,
    const float* __restrict__ g0v, const float* __restrict__ be0v,
    const float* __restrict__ g1v, const float* __restrict__ be1v,
    const float* __restrict__ wfc, const float* __restrict__ bfc,
    ull* __restrict__ pay, ull* __restrict__ pst,
    float* __restrict__ out) {

  const int blk = blockIdx.x, group = blk >> 4, p = blk & 15;
  const int tid = threadIdx.x;
  const int wave = tid >> 6, lane = tid & 63;
  const int quad = lane >> 4, m16 = lane & 15;

  // row stride 536 bf16 = 268 words: 16B-aligned rows, banks spread (268%32=12)
  __shared__ unsigned short a0bf[16][536];   // bf16 v2_0^{s-1} (rows 8..15 = 0)
  __shared__ unsigned short a1bf[16][536];   // bf16 v2_1^{s-2}
  __shared__ unsigned short xsb[16][72];     // bf16 x_s (in-place: rewritten after b1)
  __shared__ float partsA[8][8][33];         // v2_0^{s-1} @ (g0.*Wh0)
  __shared__ float partsB[8][8][33];         // v2_1^{s-2} @ (g1.*Wh1)
  __shared__ float partsC[8][8][33];         // v2_0^{s-1} @ (g0.*Wi1)
  __shared__ float partsX[2][8][33];         // x_s @ Wi0 (waves 0,1)
  __shared__ float2 st0[NCH][NBLK];          // (S,Q) of v2_0^{s-1} per publisher
  __shared__ float2 st1[NCH][NBLK];          // (S,Q) of v2_1^{s-2}

  // ---------------- init ----------------
  for (int i = tid; i < 16 * 536; i += 512) {
    (&a0bf[0][0])[i] = 0; (&a1bf[0][0])[i] = 0;
  }
  for (int i = tid; i < 16 * 72; i += 512) (&xsb[0][0])[i] = 0;
  if (tid < NCH * NBLK) {
    (&st0[0][0])[tid] = make_float2(0.f, 0.f);
    (&st1[0][0])[tid] = make_float2(0.f, 0.f);
  }
  { // x_0: thread (wave=chain, lane=d)
    float xv = x[((size_t)(group * NCH + wave) * T_SZ) * DD + lane];
    xsb[wave][lane] = f2b(xv);
  }

  // ---------------- static weight B-fragments (bf16, gamma-folded) --------
  short8 wf0[2][2], wfA[2][2], wfB[2][2], wfx[2];
#pragma unroll
  for (int n = 0; n < 2; ++n)
#pragma unroll
    for (int j = 0; j < 8; ++j) wfx[n][j] = 0;
#pragma unroll
  for (int sl = 0; sl < 2; ++sl)
#pragma unroll
    for (int n = 0; n < 2; ++n) {
      const int col = p * 32 + n * 16 + m16;
#pragma unroll
      for (int j = 0; j < 8; ++j) {
        const int k = wave * 64 + sl * 32 + quad * 8 + j;
        wf0[sl][n][j] = (short)f2b(g0v[k] * Wh0[(size_t)k * HH + col]);
        wfA[sl][n][j] = (short)f2b(g0v[k] * Wi1[(size_t)k * HH + col]);
        wfB[sl][n][j] = (short)f2b(g1v[k] * Wh1[(size_t)k * HH + col]);
      }
    }
  if (wave < 2) {
#pragma unroll
    for (int n = 0; n < 2; ++n) {
      const int col = p * 32 + n * 16 + m16;
#pragma unroll
      for (int j = 0; j < 8; ++j)
        wfx[n][j] = (short)f2b(Wi0[(size_t)(wave * 32 + quad * 8 + j) * HH + col]);
    }
  }

  // epilogue constants — loaded by ALL threads (both wave halves need them)
  const int cl    = lane & 31;
  const int ech   = ((wave & 3) << 1) + (lane >> 5);   // chain 0..7 in each half
  const int col_e = p * 32 + cl;
  const float c0f = cvec[col_e],          c0i = cvec[HH + col_e];
  const float c1f = cvec[2 * HH + col_e], c1i = cvec[3 * HH + col_e];
  const float uw0 = cvec[4 * HH + col_e], uw1 = cvec[5 * HH + col_e];
  const float uh1 = cvec[6 * HH + col_e];
  const float g0c = g0v[col_e], be0c = be0v[col_e];
  const float g1c = g1v[col_e], be1c = be1v[col_e];

  // publish bases (this thread's layer half), both parities.
  // pay layout: [blk][L][par][reader 16][ch 8][word 8]  (reader-contiguous reads)
  // pst layout: [blk][L][par][reader 16][ch 8]
  const int Lp = (wave >= 4) ? 1 : 0;
  ull* const ppayA = pay + ((((size_t)blk * 2 + Lp) * 2 + 0) * 16) * 64 + ech * 8 + (cl >> 2);
  ull* const ppayB = pay + ((((size_t)blk * 2 + Lp) * 2 + 1) * 16) * 64 + ech * 8 + (cl >> 2);
  ull* const ppstA = pst + ((((size_t)blk * 2 + Lp) * 2 + 0) * 16) * 8 + ech;
  ull* const ppstB = pst + ((((size_t)blk * 2 + Lp) * 2 + 1) * 16) * 8 + ech;
  unsigned short* const ep_lds = &((wave < 4) ? a0bf : a1bf)[ech][p * 32 + cl];

  // gather peer assignment: wave w handles peer-slots j0=2w (and j0+1 if <15)
  const int j0   = 2 * wave;
  const bool two = (j0 + 1 < 15);
  const int pg0  = j0 + (j0 >= p);
  const int pg1  = two ? ((j0 + 1) + ((j0 + 1) >= p)) : pg0;

  // -------- precomputed gather plan (both parities; statically indexed) ----
  // per-peer item space (144): [0,64)=L0 pay, [64,72)=L0 st,
  // [72,136)=L1 pay, [136,144)=L1 st.
  ull* gp0[5]; ull* gp1[5]; ull* glw[5]; bool gv[5], gva0[5];
#pragma unroll
  for (int k = 0; k < 5; ++k) {
    const int li  = lane + (k << 6);
    const int lim = two ? 288 : 144;
    const int jr  = (li >= 144) ? 1 : 0;
    const int r2  = li - 144 * jr;
    const int pl  = jr ? pg1 : pg0;
    gv[k]   = (li < lim);
    gva0[k] = gv[k] && (r2 < 72);        // at s==0 only the L0 half exists
    const int L  = (r2 >= 72) ? 1 : 0;
    const int rr = r2 - 72 * L;
    const size_t pb = ((size_t)(group * NBLK + pl) * 2 + L) * 2;   // + par
    if (rr < 64) {
      gp0[k] = pay + ((pb + 0) * 16 + p) * 64 + rr;
      gp1[k] = pay + ((pb + 1) * 16 + p) * 64 + rr;
      glw[k] = (ull*)&(L ? a1bf : a0bf)[rr >> 3][pl * 32 + 4 * (rr & 7)];
    } else {
      gp0[k] = pst + ((pb + 0) * 16 + p) * 8 + (rr - 64);
      gp1[k] = pst + ((pb + 1) * 16 + p) * 8 + (rr - 64);
      glw[k] = (ull*)&(L ? st1 : st0)[rr - 64][pl];   // float2 = 8B, same bits
    }
  }

  const float* xptr = x + ((size_t)(group * NCH + wave) * T_SZ + 1) * DD + lane;

  float v2prev0 = 0.f, v2prev1 = 0.f;
  __syncthreads();

  for (int s = 0; s <= T_SZ; ++s) {
    const int par = s & 1;

    // ---- hoisted LN stats (st0/st1 sealed by prev b3, stable till gather) --
    float m0 = 0.f, r0 = 0.f, m1p = 0.f, r1p = 0.f;
    if (s > 0) {
      float S = 0.f, Q = 0.f;
#pragma unroll
      for (int i = 0; i < NBLK; ++i) { float2 sq = st0[ech][i]; S += sq.x; Q += sq.y; }
      m0 = S * (1.f / HH);
      r0 = __builtin_amdgcn_rsqf(Q * (1.f / HH) - m0 * m0 + 1e-5f);
    }
    if (wave >= 4 && s > 1) {
      float S = 0.f, Q = 0.f;
#pragma unroll
      for (int i = 0; i < NBLK; ++i) { float2 sq = st1[ech][i]; S += sq.x; Q += sq.y; }
      m1p = S * (1.f / HH);
      r1p = __builtin_amdgcn_rsqf(Q * (1.f / HH) - m1p * m1p + 1e-5f);
    }

    // ================= phase 1 : ALL MFMAs (operands from slot s-1) ========
    {
      f32x4 aA0 = {0.f,0.f,0.f,0.f}, aA1 = {0.f,0.f,0.f,0.f};
      f32x4 aB0 = {0.f,0.f,0.f,0.f}, aB1 = {0.f,0.f,0.f,0.f};
      f32x4 aC0 = {0.f,0.f,0.f,0.f}, aC1 = {0.f,0.f,0.f,0.f};
#pragma unroll
      for (int sl = 0; sl < 2; ++sl) {
        const short8 af0 = *(const short8*)&a0bf[m16][wave * 64 + sl * 32 + quad * 8];
        const short8 af1 = *(const short8*)&a1bf[m16][wave * 64 + sl * 32 + quad * 8];
        aA0 = __builtin_amdgcn_mfma_f32_16x16x32_bf16(af0, wf0[sl][0], aA0, 0, 0, 0);
        aA1 = __builtin_amdgcn_mfma_f32_16x16x32_bf16(af0, wf0[sl][1], aA1, 0, 0, 0);
        aC0 = __builtin_amdgcn_mfma_f32_16x16x32_bf16(af0, wfA[sl][0], aC0, 0, 0, 0);
        aC1 = __builtin_amdgcn_mfma_f32_16x16x32_bf16(af0, wfA[sl][1], aC1, 0, 0, 0);
        aB0 = __builtin_amdgcn_mfma_f32_16x16x32_bf16(af1, wfB[sl][0], aB0, 0, 0, 0);
        aB1 = __builtin_amdgcn_mfma_f32_16x16x32_bf16(af1, wfB[sl][1], aB1, 0, 0, 0);
      }
      if (lane < 32) {
#pragma unroll
        for (int r = 0; r < 4; ++r) {
          partsA[wave][quad * 4 + r][m16]      = aA0[r];
          partsA[wave][quad * 4 + r][16 + m16] = aA1[r];
          partsB[wave][quad * 4 + r][m16]      = aB0[r];
          partsB[wave][quad * 4 + r][16 + m16] = aB1[r];
          partsC[wave][quad * 4 + r][m16]      = aC0[r];
          partsC[wave][quad * 4 + r][16 + m16] = aC1[r];
        }
      }
      if (wave < 2) {
        f32x4 ax0 = {0.f,0.f,0.f,0.f}, ax1 = {0.f,0.f,0.f,0.f};
        const short8 xf = *(const short8*)&xsb[m16][wave * 32 + quad * 8];
        ax0 = __builtin_amdgcn_mfma_f32_16x16x32_bf16(xf, wfx[0], ax0, 0, 0, 0);
        ax1 = __builtin_amdgcn_mfma_f32_16x16x32_bf16(xf, wfx[1], ax1, 0, 0, 0);
        if (lane < 32) {
#pragma unroll
          for (int r = 0; r < 4; ++r) {
            partsX[wave][quad * 4 + r][m16]      = ax0[r];
            partsX[wave][quad * 4 + r][16 + m16] = ax1[r];
          }
        }
      }
    }
    __syncthreads();                                    // b1

    // ===== parallel epilogues: waves 0-3 = L0 step s | waves 4-7 = L1 step s-1
    if (wave < 4) {
      if (s < T_SZ) {
        float sH = 0.f;
#pragma unroll
        for (int w = 0; w < 8; ++w) sH += partsA[w][ech][cl];
        const float sX = partsX[0][ech][cl] + partsX[1][ech][cl];
        const float z = ((s == 0) ? c0i : c0f) + r0 * sH - r0 * m0 * uw0 + sX;
        const float h0prev = (s == 0) ? 0.f : (v2prev0 - m0) * r0 * g0c + be0c;
        const float v2 = fast_tanh(z) + h0prev;
        v2prev0 = v2;
        const unsigned vb = f2b(v2);
        *ep_lds = (unsigned short)vb;
        const unsigned u01 = vb | (__shfl_down(vb, 1) << 16);
        const unsigned u23 = __shfl_down(u01, 2);
        if ((cl & 3) == 0) {
          const ull v = (ull)u01 | ((ull)u23 << 32);
          ull* b = par ? ppayB : ppayA;
#pragma unroll
          for (int r = 0; r < 16; ++r) st_rlx(b + r * 64, v);
        }
        float S = v2, Q = v2 * v2;
#pragma unroll
        for (int off = 16; off; off >>= 1) {
          S += __shfl_down(S, off, 32); Q += __shfl_down(Q, off, 32);
        }
        if (cl == 0) {
          st0[ech][p] = make_float2(S, Q);   // safe: all st0 reads hoisted before b1
          const ull v = packf2(S, Q);
          ull* b = par ? ppstB : ppstA;
#pragma unroll
          for (int r = 0; r < 16; ++r) st_rlx(b + r * 8, v);
        }
      }
    } else if (s >= 1) {
      float sB = 0.f, sC = 0.f;
#pragma unroll
      for (int w = 0; w < 8; ++w) { sB += partsB[w][ech][cl]; sC += partsC[w][ech][cl]; }
      const float z = ((s == 1) ? c1i : c1f) + r0 * sC - r0 * m0 * uw1
                      + r1p * sB - r1p * m1p * uh1;
      const float h1prev = (s == 1) ? 0.f : (v2prev1 - m1p) * r1p * g1c + be1c;
      const float v2 = fast_tanh(z) + h1prev;
      v2prev1 = v2;
      const unsigned vb = f2b(v2);
      *ep_lds = (unsigned short)vb;
      const unsigned u01 = vb | (__shfl_down(vb, 1) << 16);
      const unsigned u23 = __shfl_down(u01, 2);
      if ((cl & 3) == 0) {
        const ull v = (ull)u01 | ((ull)u23 << 32);
        ull* b = par ? ppayB : ppayA;
#pragma unroll
        for (int r = 0; r < 16; ++r) st_rlx(b + r * 64, v);
      }
      float S = v2, Q = v2 * v2;
#pragma unroll
      for (int off = 16; off; off >>= 1) {
        S += __shfl_down(S, off, 32); Q += __shfl_down(Q, off, 32);
      }
      if (cl == 0) {
        st1[ech][p] = make_float2(S, Q);
        const ull v = packf2(S, Q);
        ull* b = par ? ppstB : ppstA;
#pragma unroll
        for (int r = 0; r < 16; ++r) st_rlx(b + r * 8, v);
      }
    }
    if (s == T_SZ) break;

    // x prefetch issue (consumed after b3 barrier next slot)
    float xv = 0.f;
    if (s + 1 < T_SZ) xv = *xptr;
    xptr += DD;

    // -------- sentinel gather: poll private copies, consume, re-sentinel ----
    {
      bool need[5];
#pragma unroll
      for (int k = 0; k < 5; ++k) need[k] = s ? gv[k] : gva0[k];
      for (;;) {
        bool any = false;
#pragma unroll
        for (int k = 0; k < 5; ++k) {
          if (need[k]) {
            ull* ap = par ? gp1[k] : gp0[k];
            const ull v = ld_rlx(ap);
            if (v != SENT) {
              need[k] = false;
              st_rlx(ap, SENT);       // re-arm private copy (drained by b3)
              *glw[k] = v;
            } else any = true;
          }
        }
        if (!any) break;
        __builtin_amdgcn_s_sleep(1);
      }
    }
    if (s + 1 < T_SZ) xsb[wave][lane] = f2b(xv);
    __syncthreads();                                    // b3
  }

  // ============ head (p==0 blocks): out = LN(v2_1^{T-1}).Wfc + bfc ========
  // v2_1^{T-1} published at slot T (par=0). Own block's share from LDS
  // (a1bf/st1 — self-slot words are never re-sentineled so LDS is the only
  // stale-proof source); peers via sentinel-poll at reader slot 0 (= our p).
  if (p == 0) {
    __syncthreads();   // seal slot-T epilogue LDS writes (a1bf, st1)
    const int c = wave;   // wave handles chain c
    ull su = 0;
    if (lane < 16) {
      if (lane == 0) {
        float2 sq = st1[c][0];
        su = packf2(sq.x, sq.y);
      } else {
        const ull* a = pst + ((((size_t)(group * NBLK + lane) * 2 + 1) * 2 + 0) * 16 + 0) * 8 + c;
        for (;;) { su = ld_rlx(a); if (su != SENT) break; __builtin_amdgcn_s_sleep(1); }
      }
    }
    float S = unpack_lo(su), Q = unpack_hi(su);
#pragma unroll
    for (int off = 32; off; off >>= 1) { S += __shfl_down(S, off); Q += __shfl_down(Q, off); }
    S = __shfl(S, 0); Q = __shfl(Q, 0);
    const float m1 = S * (1.f / HH);
    const float r1 = 1.f / sqrtf(Q * (1.f / HH) - m1 * m1 + 1e-5f);
    float o = 0.f;
#pragma unroll
    for (int it = 0; it < 2; ++it) {
      const int j2 = lane * 2 + it, pl = j2 >> 3, j = j2 & 7;
      ull u;
      if (pl == 0) {
        u = *(const ull*)&a1bf[c][4 * j];
      } else {
        const ull* a = pay + ((((size_t)(group * NBLK + pl) * 2 + 1) * 2 + 0) * 16 + 0) * 64 + c * 8 + j;
        for (;;) { u = ld_rlx(a); if (u != SENT) break; __builtin_amdgcn_s_sleep(1); }
      }
#pragma unroll
      for (int q = 0; q < 4; ++q) {
        const int col = pl * 32 + 4 * j + q;
        const float h = (b2f((unsigned short)(u >> (16 * q))) - m1) * r1 * g1v[col] + be1v[col];
        o += h * wfc[col];
      }
    }
#pragma unroll
    for (int off = 32; off; off >>= 1) o += __shfl_down(o, off);
    if (lane == 0) out[group * NCH + c] = o + bfc[0];
  }
}

extern "C" void kernel_launch(void* const* d_in, const int* in_sizes, int n_in,
                              void* d_out, int out_size, void* d_ws, size_t ws_size,
                              hipStream_t stream) {
  const float* x   = (const float*)d_in[0];
  const float* Wi0 = (const float*)d_in[1];
  const float* bi0 = (const float*)d_in[2];
  const float* Wh0 = (const float*)d_in[3];
  const float* bh0 = (const float*)d_in[4];
  const float* g0  = (const float*)d_in[5];
  const float* be0 = (const float*)d_in[6];
  const float* Wi1 = (const float*)d_in[7];
  const float* bi1 = (const float*)d_in[8];
  const float* Wh1 = (const float*)d_in[9];
  const float* bh1 = (const float*)d_in[10];
  const float* g1  = (const float*)d_in[11];
  const float* be1 = (const float*)d_in[12];
  const float* Wfc = (const float*)d_in[13];
  const float* bfc = (const float*)d_in[14];
  float* out = (float*)d_out;

  // ws: cvec 16KB | pay 8MB (256blk x 2L x 2par x 16rd x 64w x 8B) | pst 1MB
  char* ws = (char*)d_ws;
  float* cvec = (float*)(ws);
  ull* pay    = (ull*)(ws + 16384);
  ull* pst    = (ull*)(ws + 16384 + 8388608);

  prep_kernel<<<256, 256, 0, stream>>>(Wh0, Wi1, Wh1, bi0, bh0, bi1, bh1,
                                       g0, be0, g1, be1, cvec, pay, pst);
  rnn_mfma<<<256, 512, 0, stream>>>(x, Wi0, Wh0, Wi1, Wh1, cvec,
                                    g0, be0, g1, be1, Wfc, bfc,
                                    pay, pst, out);
}

// Round 5
// 5241.584 us; speedup vs baseline: 1.2694x; 1.2694x over previous
//
#include <hip/hip_runtime.h>

// ResidualSkipRNNForecaster — R11: self-tagged payload words (single copy,
// zero flags, zero reader stores, one one-way latency per slot).
//
// R10 post-mortem: x16 replication + re-sentinel = 12.9GB HBM writes @2TB/s
// = the whole 6.6ms. Mechanism (payload-as-flag) was right; replication paid
// for it in bandwidth. R11: every 64-bit word self-announces its slot:
//   pay word  = 3x bf16 | tag16(s+1) << 48     (11 words per 32-value row)
//   stat word = f32     | tag32(s+1) << 32     (S and Q separate words)
// Readers poll the SINGLE shared copy until tag==s+1. Stale data from the
// same parity buffer has tag s-1 — distinguishable, so no re-arm stores.
// Parity-2 buffers + skew<=1 induction (unchanged from R7-R9): we at slot s
// => we observed every peer's tag-s words => peer passed b3(s-2) => peer
// finished reading buffer par(s) before our overwriting stores were issued.
// Also proves no-deadlock (no reader can still want tag s-1 when we
// overwrite). 2 barriers/slot (b1, b3). Write traffic 0.44GB total.

#define T_SZ 1024
#define DD   64
#define HH   512
#define NCH  8
#define NBLK 16
#define SENT 0xFFFFFFFFFFFFFFFFull
#define PAYW 104                       // words per (blk,L,par): 8 ch x 13
#define TOTW (256 * 2 * 2 * PAYW)      // 106496 words = 852KB

typedef __attribute__((ext_vector_type(8))) short short8;
typedef __attribute__((ext_vector_type(4))) float f32x4;
typedef unsigned long long ull;

__device__ __forceinline__ unsigned short f2b(float f) {
  unsigned u = __float_as_uint(f);
  u += 0x7fffu + ((u >> 16) & 1u);   // RNE
  return (unsigned short)(u >> 16);
}
__device__ __forceinline__ float b2f(unsigned short s) {
  return __uint_as_float(((unsigned)s) << 16);
}
__device__ __forceinline__ void st_rlx(ull* p, ull v) {
  __hip_atomic_store(p, v, __ATOMIC_RELAXED, __HIP_MEMORY_SCOPE_AGENT);
}
__device__ __forceinline__ ull ld_rlx(const ull* p) {
  return __hip_atomic_load(p, __ATOMIC_RELAXED, __HIP_MEMORY_SCOPE_AGENT);
}
// tanh(z) = 1 - 2/(e^{2z}+1), exact; exp2+rcp HW approx (~1e-7 abs err).
__device__ __forceinline__ float fast_tanh(float z) {
  const float e = __builtin_amdgcn_exp2f(z * 2.885390081777927f);  // e^{2z}
  return 1.f - 2.f * __builtin_amdgcn_rcpf(e + 1.f);
}

__global__ void prep_kernel(const float* __restrict__ Wh0, const float* __restrict__ Wi1,
                            const float* __restrict__ Wh1,
                            const float* __restrict__ bi0, const float* __restrict__ bh0,
                            const float* __restrict__ bi1, const float* __restrict__ bh1,
                            const float* __restrict__ g0, const float* __restrict__ be0,
                            const float* __restrict__ g1, const float* __restrict__ be1,
                            float* __restrict__ cvec, ull* __restrict__ pay) {
  int g = blockIdx.x * blockDim.x + threadIdx.x;
  if (g < HH) {
    float uw0 = 0.f, qw0 = 0.f, uw1 = 0.f, qw1 = 0.f, uh1 = 0.f, qh1 = 0.f;
    for (int j = 0; j < HH; ++j) {
      float a = Wh0[j * HH + g], b = Wi1[j * HH + g], d = Wh1[j * HH + g];
      uw0 += g0[j] * a; qw0 += be0[j] * a;
      uw1 += g0[j] * b; qw1 += be0[j] * b;
      uh1 += g1[j] * d; qh1 += be1[j] * d;
    }
    float b0 = bi0[g] + bh0[g], b1 = bi1[g] + bh1[g];
    cvec[0 * HH + g] = b0 + qw0;        // c0 full (t>0)
    cvec[1 * HH + g] = b0;              // c0 init (t==0)
    cvec[2 * HH + g] = b1 + qw1 + qh1;  // c1 full
    cvec[3 * HH + g] = b1 + qw1;        // c1 init
    cvec[4 * HH + g] = uw0;
    cvec[5 * HH + g] = uw1;
    cvec[6 * HH + g] = uh1;
  }
  const int base = g * 2;               // 65536 threads x 2 >= TOTW
#pragma unroll
  for (int i = 0; i < 2; ++i)
    if (base + i < TOTW) pay[base + i] = SENT;   // tag fields = 0xFFFF/0xFFFFFFFF
}

__global__ __launch_bounds__(512, 1) void rnn_mfma(
    const float* __restrict__ x,
    const float* __restrict__ Wi0, const float* __restrict__ Wh0,
    const float* __restrict__ Wi1, const float* __restrict__ Wh1,
    const float* __restrict__ cvec,
    const float* __restrict__ g0v, const float* __restrict__ be0v,
    const float* __restrict__ g1v, const float* __restrict__ be1v,
    const float* __restrict__ wfc, const float* __restrict__ bfc,
    ull* __restrict__ pay, float* __restrict__ out) {

  const int blk = blockIdx.x, group = blk >> 4, p = blk & 15;
  const int tid = threadIdx.x;
  const int wave = tid >> 6, lane = tid & 63;
  const int quad = lane >> 4, m16 = lane & 15;

  // row stride 536 bf16 = 268 words: 16B-aligned rows, banks spread (268%32=12)
  __shared__ unsigned short a0bf[16][536];   // bf16 v2_0^{s-1} (rows 8..15 = 0)
  __shared__ unsigned short a1bf[16][536];   // bf16 v2_1^{s-2}
  __shared__ unsigned short xsb[16][72];     // bf16 x_s (rewritten after b1)
  __shared__ float partsA[8][8][33];         // v2_0^{s-1} @ (g0.*Wh0)
  __shared__ float partsB[8][8][33];         // v2_1^{s-2} @ (g1.*Wh1)
  __shared__ float partsC[8][8][33];         // v2_0^{s-1} @ (g0.*Wi1)
  __shared__ float partsX[2][8][33];         // x_s @ Wi0 (waves 0,1)
  __shared__ float2 st0[NCH][NBLK];          // (S,Q) of v2_0^{s-1} per publisher
  __shared__ float2 st1[NCH][NBLK];          // (S,Q) of v2_1^{s-2}

  // ---------------- init ----------------
  for (int i = tid; i < 16 * 536; i += 512) {
    (&a0bf[0][0])[i] = 0; (&a1bf[0][0])[i] = 0;
  }
  for (int i = tid; i < 16 * 72; i += 512) (&xsb[0][0])[i] = 0;
  if (tid < NCH * NBLK) {
    (&st0[0][0])[tid] = make_float2(0.f, 0.f);
    (&st1[0][0])[tid] = make_float2(0.f, 0.f);
  }
  { // x_0: thread (wave=chain, lane=d)
    float xv = x[((size_t)(group * NCH + wave) * T_SZ) * DD + lane];
    xsb[wave][lane] = f2b(xv);
  }

  // ---------------- static weight B-fragments (bf16, gamma-folded) --------
  short8 wf0[2][2], wfA[2][2], wfB[2][2], wfx[2];
#pragma unroll
  for (int n = 0; n < 2; ++n)
#pragma unroll
    for (int j = 0; j < 8; ++j) wfx[n][j] = 0;
#pragma unroll
  for (int sl = 0; sl < 2; ++sl)
#pragma unroll
    for (int n = 0; n < 2; ++n) {
      const int col = p * 32 + n * 16 + m16;
#pragma unroll
      for (int j = 0; j < 8; ++j) {
        const int k = wave * 64 + sl * 32 + quad * 8 + j;
        wf0[sl][n][j] = (short)f2b(g0v[k] * Wh0[(size_t)k * HH + col]);
        wfA[sl][n][j] = (short)f2b(g0v[k] * Wi1[(size_t)k * HH + col]);
        wfB[sl][n][j] = (short)f2b(g1v[k] * Wh1[(size_t)k * HH + col]);
      }
    }
  if (wave < 2) {
#pragma unroll
    for (int n = 0; n < 2; ++n) {
      const int col = p * 32 + n * 16 + m16;
#pragma unroll
      for (int j = 0; j < 8; ++j)
        wfx[n][j] = (short)f2b(Wi0[(size_t)(wave * 32 + quad * 8 + j) * HH + col]);
    }
  }

  // epilogue constants — loaded by ALL threads (both wave halves need them)
  const int cl    = lane & 31;
  const int ech   = ((wave & 3) << 1) + (lane >> 5);   // chain 0..7 in each half
  const int col_e = p * 32 + cl;
  const float c0f = cvec[col_e],          c0i = cvec[HH + col_e];
  const float c1f = cvec[2 * HH + col_e], c1i = cvec[3 * HH + col_e];
  const float uw0 = cvec[4 * HH + col_e], uw1 = cvec[5 * HH + col_e];
  const float uh1 = cvec[6 * HH + col_e];
  const float g0c = g0v[col_e], be0c = be0v[col_e];
  const float g1c = g1v[col_e], be1c = be1v[col_e];

  // publisher plan: row base for this thread's (layer-half, chain-row)
  const int Lp = (wave >= 4) ? 1 : 0;
  ull* const prow0 = pay + (((size_t)blk * 2 + Lp) * 2 + 0) * PAYW + ech * 13;
  ull* const prow1 = prow0 + PAYW;
  const bool ispub = (cl % 3 == 0);        // lanes cl = 0,3,...,30 (11 per half)
  const int  jw    = cl / 3;               // word index 0..10
  unsigned short* const ep_lds = &((wave < 4) ? a0bf : a1bf)[ech][p * 32 + cl];

  // -------- gather plan: 3120 items = 15 peers x 2L x 8ch x 13w ----------
  const ull* gsrc[7]; void* gdst[7]; int gtype[7]; bool gL1[7];
#pragma unroll
  for (int k = 0; k < 7; ++k) {
    const int idx   = tid + (k << 9);
    const bool valid = idx < 15 * 208;
    const int cidx  = valid ? idx : 0;
    const int pi = cidx / 208, r = cidx - pi * 208;
    const int pl = pi + (pi >= p);
    const int L  = r / 104, rr = r - L * 104;
    const int ch = rr / 13, w = rr - ch * 13;
    gsrc[k] = pay + (((size_t)(group * NBLK + pl) * 2 + L) * 2 + 0) * PAYW + ch * 13 + w;
    gL1[k]  = (L == 1);
    if (!valid) { gtype[k] = 255; gdst[k] = (void*)&a0bf[0][0]; }
    else if (w < 11) {
      gtype[k] = (w == 10) ? 1 : 0;
      gdst[k] = (void*)&(L ? a1bf : a0bf)[ch][pl * 32 + 3 * w];
    } else {
      gtype[k] = 2;
      gdst[k] = (w == 11) ? (void*)&(L ? st1 : st0)[ch][pl].x
                          : (void*)&(L ? st1 : st0)[ch][pl].y;
    }
  }

  const float* xptr = x + ((size_t)(group * NCH + wave) * T_SZ + 1) * DD + lane;

  float v2prev0 = 0.f, v2prev1 = 0.f;
  __syncthreads();

  for (int s = 0; s <= T_SZ; ++s) {
    const int par = s & 1;
    const unsigned et = (unsigned)(s + 1);

    // ---- hoisted LN stats (st0/st1 sealed by prev b3, stable till gather) --
    float m0 = 0.f, r0 = 0.f, m1p = 0.f, r1p = 0.f;
    if (s > 0) {
      float S = 0.f, Q = 0.f;
#pragma unroll
      for (int i = 0; i < NBLK; ++i) { float2 sq = st0[ech][i]; S += sq.x; Q += sq.y; }
      m0 = S * (1.f / HH);
      r0 = __builtin_amdgcn_rsqf(Q * (1.f / HH) - m0 * m0 + 1e-5f);
    }
    if (wave >= 4 && s > 1) {
      float S = 0.f, Q = 0.f;
#pragma unroll
      for (int i = 0; i < NBLK; ++i) { float2 sq = st1[ech][i]; S += sq.x; Q += sq.y; }
      m1p = S * (1.f / HH);
      r1p = __builtin_amdgcn_rsqf(Q * (1.f / HH) - m1p * m1p + 1e-5f);
    }

    // ================= phase 1 : ALL MFMAs (operands from slot s-1) ========
    {
      f32x4 aA0 = {0.f,0.f,0.f,0.f}, aA1 = {0.f,0.f,0.f,0.f};
      f32x4 aB0 = {0.f,0.f,0.f,0.f}, aB1 = {0.f,0.f,0.f,0.f};
      f32x4 aC0 = {0.f,0.f,0.f,0.f}, aC1 = {0.f,0.f,0.f,0.f};
#pragma unroll
      for (int sl = 0; sl < 2; ++sl) {
        const short8 af0 = *(const short8*)&a0bf[m16][wave * 64 + sl * 32 + quad * 8];
        const short8 af1 = *(const short8*)&a1bf[m16][wave * 64 + sl * 32 + quad * 8];
        aA0 = __builtin_amdgcn_mfma_f32_16x16x32_bf16(af0, wf0[sl][0], aA0, 0, 0, 0);
        aA1 = __builtin_amdgcn_mfma_f32_16x16x32_bf16(af0, wf0[sl][1], aA1, 0, 0, 0);
        aC0 = __builtin_amdgcn_mfma_f32_16x16x32_bf16(af0, wfA[sl][0], aC0, 0, 0, 0);
        aC1 = __builtin_amdgcn_mfma_f32_16x16x32_bf16(af0, wfA[sl][1], aC1, 0, 0, 0);
        aB0 = __builtin_amdgcn_mfma_f32_16x16x32_bf16(af1, wfB[sl][0], aB0, 0, 0, 0);
        aB1 = __builtin_amdgcn_mfma_f32_16x16x32_bf16(af1, wfB[sl][1], aB1, 0, 0, 0);
      }
      if (lane < 32) {
#pragma unroll
        for (int r = 0; r < 4; ++r) {
          partsA[wave][quad * 4 + r][m16]      = aA0[r];
          partsA[wave][quad * 4 + r][16 + m16] = aA1[r];
          partsB[wave][quad * 4 + r][m16]      = aB0[r];
          partsB[wave][quad * 4 + r][16 + m16] = aB1[r];
          partsC[wave][quad * 4 + r][m16]      = aC0[r];
          partsC[wave][quad * 4 + r][16 + m16] = aC1[r];
        }
      }
      if (wave < 2) {
        f32x4 ax0 = {0.f,0.f,0.f,0.f}, ax1 = {0.f,0.f,0.f,0.f};
        const short8 xf = *(const short8*)&xsb[m16][wave * 32 + quad * 8];
        ax0 = __builtin_amdgcn_mfma_f32_16x16x32_bf16(xf, wfx[0], ax0, 0, 0, 0);
        ax1 = __builtin_amdgcn_mfma_f32_16x16x32_bf16(xf, wfx[1], ax1, 0, 0, 0);
        if (lane < 32) {
#pragma unroll
          for (int r = 0; r < 4; ++r) {
            partsX[wave][quad * 4 + r][m16]      = ax0[r];
            partsX[wave][quad * 4 + r][16 + m16] = ax1[r];
          }
        }
      }
    }
    __syncthreads();                                    // b1

    // ===== parallel epilogues: waves 0-3 = L0 step s | waves 4-7 = L1 step s-1
    if (wave < 4) {
      if (s < T_SZ) {
        float sH = 0.f;
#pragma unroll
        for (int w = 0; w < 8; ++w) sH += partsA[w][ech][cl];
        const float sX = partsX[0][ech][cl] + partsX[1][ech][cl];
        const float z = ((s == 0) ? c0i : c0f) + r0 * sH - r0 * m0 * uw0 + sX;
        const float h0prev = (s == 0) ? 0.f : (v2prev0 - m0) * r0 * g0c + be0c;
        const float v2 = fast_tanh(z) + h0prev;
        v2prev0 = v2;
        const unsigned vb = f2b(v2);
        *ep_lds = (unsigned short)vb;
        const unsigned v1s = __shfl_down(vb, 1), v2s = __shfl_down(vb, 2);
        ull* const pr = par ? prow1 : prow0;
        if (ispub)
          st_rlx(pr + jw, (ull)vb | ((ull)v1s << 16) |
                          (jw < 10 ? ((ull)v2s << 32) : 0ull) | ((ull)et << 48));
        float S = v2, Q = v2 * v2;
#pragma unroll
        for (int off = 16; off; off >>= 1) {
          S += __shfl_down(S, off, 32); Q += __shfl_down(Q, off, 32);
        }
        if (cl == 0) {
          st0[ech][p] = make_float2(S, Q);   // safe: all st0 reads hoisted pre-b1
          st_rlx(pr + 11, (ull)__float_as_uint(S) | ((ull)et << 32));
          st_rlx(pr + 12, (ull)__float_as_uint(Q) | ((ull)et << 32));
        }
      }
    } else if (s >= 1) {
      float sB = 0.f, sC = 0.f;
#pragma unroll
      for (int w = 0; w < 8; ++w) { sB += partsB[w][ech][cl]; sC += partsC[w][ech][cl]; }
      const float z = ((s == 1) ? c1i : c1f) + r0 * sC - r0 * m0 * uw1
                      + r1p * sB - r1p * m1p * uh1;
      const float h1prev = (s == 1) ? 0.f : (v2prev1 - m1p) * r1p * g1c + be1c;
      const float v2 = fast_tanh(z) + h1prev;
      v2prev1 = v2;
      const unsigned vb = f2b(v2);
      *ep_lds = (unsigned short)vb;
      const unsigned v1s = __shfl_down(vb, 1), v2s = __shfl_down(vb, 2);
      ull* const pr = par ? prow1 : prow0;
      if (ispub)
        st_rlx(pr + jw, (ull)vb | ((ull)v1s << 16) |
                        (jw < 10 ? ((ull)v2s << 32) : 0ull) | ((ull)et << 48));
      float S = v2, Q = v2 * v2;
#pragma unroll
      for (int off = 16; off; off >>= 1) {
        S += __shfl_down(S, off, 32); Q += __shfl_down(Q, off, 32);
      }
      if (cl == 0) {
        st1[ech][p] = make_float2(S, Q);
        st_rlx(pr + 11, (ull)__float_as_uint(S) | ((ull)et << 32));
        st_rlx(pr + 12, (ull)__float_as_uint(Q) | ((ull)et << 32));
      }
    }
    if (s == T_SZ) break;

    // x prefetch issue (consumed after b3 barrier next slot)
    float xv = 0.f;
    if (s + 1 < T_SZ) xv = *xptr;
    xptr += DD;

    // -------- tagged gather: poll shared words until tag == s+1 ------------
    {
      bool need[7];
#pragma unroll
      for (int k = 0; k < 7; ++k) need[k] = (gtype[k] != 255) && (s > 0 || !gL1[k]);
      for (;;) {
        bool any = false;
#pragma unroll
        for (int k = 0; k < 7; ++k) {
          if (need[k]) {
            const ull u = ld_rlx(gsrc[k] + (par ? PAYW : 0));
            const bool ok = (gtype[k] < 2) ? ((u >> 48) == (ull)et)
                                           : ((u >> 32) == (ull)et);
            if (ok) {
              need[k] = false;
              if (gtype[k] < 2) {
                unsigned short* d = (unsigned short*)gdst[k];
                d[0] = (unsigned short)u;
                d[1] = (unsigned short)(u >> 16);
                if (gtype[k] == 0) d[2] = (unsigned short)(u >> 32);
              } else {
                *(float*)gdst[k] = __uint_as_float((unsigned)u);
              }
            } else any = true;
          }
        }
        if (!any) break;
        __builtin_amdgcn_s_sleep(2);
      }
    }
    if (s + 1 < T_SZ) xsb[wave][lane] = f2b(xv);
    __syncthreads();                                    // b3
  }

  // ============ head (p==0 blocks): out = LN(v2_1^{T-1}).Wfc + bfc ========
  // v2_1^{T-1} published at slot T (par=0, tag T+1). Own block's share from
  // LDS (a1bf/st1, sealed by the barrier below); peers via tagged polls.
  if (p == 0) {
    __syncthreads();   // seal slot-T epilogue LDS writes (a1bf, st1)
    const int c = wave;   // wave handles chain c
    const unsigned etH = (unsigned)(T_SZ + 1);
    float Sp = 0.f, Qp = 0.f;
    if (lane < 30) {
      const int pl = 1 + (lane >> 1), which = lane & 1;
      const ull* a = pay + (((size_t)(group * NBLK + pl) * 2 + 1) * 2 + 0) * PAYW
                         + c * 13 + 11 + which;
      ull u;
      for (;;) { u = ld_rlx(a); if ((u >> 32) == (ull)etH) break; __builtin_amdgcn_s_sleep(4); }
      const float v = __uint_as_float((unsigned)u);
      if (which == 0) Sp = v; else Qp = v;
    }
#pragma unroll
    for (int off = 32; off; off >>= 1) { Sp += __shfl_down(Sp, off); Qp += __shfl_down(Qp, off); }
    const float2 own = st1[c][0];
    const float Stot = __shfl(Sp, 0) + own.x;
    const float Qtot = __shfl(Qp, 0) + own.y;
    const float m1 = Stot * (1.f / HH);
    const float r1 = __builtin_amdgcn_rsqf(Qtot * (1.f / HH) - m1 * m1 + 1e-5f);
    float o = 0.f;
    if (lane < 32)
      o = ((b2f(a1bf[c][lane]) - m1) * r1 * g1v[lane] + be1v[lane]) * wfc[lane];
#pragma unroll
    for (int it = 0; it < 3; ++it) {
      const int idx = lane + (it << 6);
      if (idx < 165) {                      // 15 peers x 11 payload words
        const int pl = 1 + idx / 11, w = idx - (pl - 1) * 11;
        const ull* a = pay + (((size_t)(group * NBLK + pl) * 2 + 1) * 2 + 0) * PAYW
                           + c * 13 + w;
        ull u;
        for (;;) { u = ld_rlx(a); if ((u >> 48) == (ull)etH) break; __builtin_amdgcn_s_sleep(4); }
#pragma unroll
        for (int q = 0; q < 3; ++q) {
          if (3 * w + q < 32) {
            const int col = pl * 32 + 3 * w + q;
            o += ((b2f((unsigned short)(u >> (16 * q))) - m1) * r1 * g1v[col]
                  + be1v[col]) * wfc[col];
          }
        }
      }
    }
#pragma unroll
    for (int off = 32; off; off >>= 1) o += __shfl_down(o, off);
    if (lane == 0) out[group * NCH + c] = o + bfc[0];
  }
}

extern "C" void kernel_launch(void* const* d_in, const int* in_sizes, int n_in,
                              void* d_out, int out_size, void* d_ws, size_t ws_size,
                              hipStream_t stream) {
  const float* x   = (const float*)d_in[0];
  const float* Wi0 = (const float*)d_in[1];
  const float* bi0 = (const float*)d_in[2];
  const float* Wh0 = (const float*)d_in[3];
  const float* bh0 = (const float*)d_in[4];
  const float* g0  = (const float*)d_in[5];
  const float* be0 = (const float*)d_in[6];
  const float* Wi1 = (const float*)d_in[7];
  const float* bi1 = (const float*)d_in[8];
  const float* Wh1 = (const float*)d_in[9];
  const float* bh1 = (const float*)d_in[10];
  const float* g1  = (const float*)d_in[11];
  const float* be1 = (const float*)d_in[12];
  const float* Wfc = (const float*)d_in[13];
  const float* bfc = (const float*)d_in[14];
  float* out = (float*)d_out;

  // ws: cvec 16KB | pay 852KB (tagged words, single copy)
  char* ws = (char*)d_ws;
  float* cvec = (float*)(ws);
  ull* pay    = (ull*)(ws + 16384);

  prep_kernel<<<256, 256, 0, stream>>>(Wh0, Wi1, Wh1, bi0, bh0, bi1, bh1,
                                       g0, be0, g1, be1, cvec, pay);
  rnn_mfma<<<256, 512, 0, stream>>>(x, Wi0, Wh0, Wi1, Wh1, cvec,
                                    g0, be0, g1, be1, Wfc, bfc,
                                    pay, out);
}

// Round 6
// 4336.473 us; speedup vs baseline: 1.5344x; 1.2087x over previous
//
#include <hip/hip_runtime.h>

// ResidualSkipRNNForecaster — R12: R9 skeleton + per-wave drain-and-tag
// (no block-wide rendezvous, 2 barriers/slot, tiny poll traffic).
//
// R11 post-mortem: polling 3120 tagged words = max over 3120 arrivals + load
// storm per retry (3.5K loads/block/round). R9's b2-drain compressed the tail
// publisher-side (flag visible => payload durable) — keep that property, drop
// the block-wide cost. R12:
//   1. Per-WAVE: payload stores -> s_waitcnt vmcnt(0) (own ~18 stores only,
//      no barrier) -> lane0 relaxed tag store tags[blk][wave]=s+1. Payload
//      durable at MALL before tag issues.
//   2. Block's 8 tags = one 64B line. Reader wave polls its 2 peers' lines
//      (16 lanes, one tag each, >= s+1, __all) — 2 line-loads per retry.
//      Then R9's register-staged burst gather (5 loads -> 5 LDS stores).
//   3. b2 deleted (per-wave drain replaces it): barriers/slot 3 -> 2.
//      Stats LDS writes direct in epilogue (st0/st1 reads all hoisted pre-b1).
// Parity-2 + monotone-tag induction: overwriting par(s) at slot s+2 requires
// observing all peers' tag s+2 => peers finished gather(s). Tag '>=' correct
// (skew<=1 bounds tags at s+3, opposite parity).

#define T_SZ 1024
#define DD   64
#define HH   512
#define NCH  8
#define NBLK 16

typedef __attribute__((ext_vector_type(8))) short short8;
typedef __attribute__((ext_vector_type(4))) float f32x4;
typedef unsigned long long ull;

__device__ __forceinline__ unsigned short f2b(float f) {
  unsigned u = __float_as_uint(f);
  u += 0x7fffu + ((u >> 16) & 1u);   // RNE
  return (unsigned short)(u >> 16);
}
__device__ __forceinline__ float b2f(unsigned short s) {
  return __uint_as_float(((unsigned)s) << 16);
}
__device__ __forceinline__ ull packf2(float a, float b) {
  return (ull)__float_as_uint(a) | ((ull)__float_as_uint(b) << 32);
}
__device__ __forceinline__ float unpack_lo(ull u) { return __uint_as_float((unsigned)u); }
__device__ __forceinline__ float unpack_hi(ull u) { return __uint_as_float((unsigned)(u >> 32)); }
__device__ __forceinline__ void st_rlx(ull* p, ull v) {
  __hip_atomic_store(p, v, __ATOMIC_RELAXED, __HIP_MEMORY_SCOPE_AGENT);
}
__device__ __forceinline__ ull ld_rlx(const ull* p) {
  return __hip_atomic_load(p, __ATOMIC_RELAXED, __HIP_MEMORY_SCOPE_AGENT);
}
// tanh(z) = 1 - 2/(e^{2z}+1), exact; exp2+rcp HW approx (~1e-7 abs err).
__device__ __forceinline__ float fast_tanh(float z) {
  const float e = __builtin_amdgcn_exp2f(z * 2.885390081777927f);  // e^{2z}
  return 1.f - 2.f * __builtin_amdgcn_rcpf(e + 1.f);
}

__global__ void prep_kernel(const float* __restrict__ Wh0, const float* __restrict__ Wi1,
                            const float* __restrict__ Wh1,
                            const float* __restrict__ bi0, const float* __restrict__ bh0,
                            const float* __restrict__ bi1, const float* __restrict__ bh1,
                            const float* __restrict__ g0, const float* __restrict__ be0,
                            const float* __restrict__ g1, const float* __restrict__ be1,
                            float* __restrict__ cvec, ull* __restrict__ tags) {
  int g = blockIdx.x * blockDim.x + threadIdx.x;
  if (g < HH) {
    float uw0 = 0.f, qw0 = 0.f, uw1 = 0.f, qw1 = 0.f, uh1 = 0.f, qh1 = 0.f;
    for (int j = 0; j < HH; ++j) {
      float a = Wh0[j * HH + g], b = Wi1[j * HH + g], d = Wh1[j * HH + g];
      uw0 += g0[j] * a; qw0 += be0[j] * a;
      uw1 += g0[j] * b; qw1 += be0[j] * b;
      uh1 += g1[j] * d; qh1 += be1[j] * d;
    }
    float b0 = bi0[g] + bh0[g], b1 = bi1[g] + bh1[g];
    cvec[0 * HH + g] = b0 + qw0;        // c0 full (t>0)
    cvec[1 * HH + g] = b0;              // c0 init (t==0)
    cvec[2 * HH + g] = b1 + qw1 + qh1;  // c1 full
    cvec[3 * HH + g] = b1 + qw1;        // c1 init
    cvec[4 * HH + g] = uw0;
    cvec[5 * HH + g] = uw1;
    cvec[6 * HH + g] = uh1;
  }
  if (g < 2048) tags[g] = 0;            // 256 blocks x 8 wave-tags
}

__global__ __launch_bounds__(512, 1) void rnn_mfma(
    const float* __restrict__ x,
    const float* __restrict__ Wi0, const float* __restrict__ Wh0,
    const float* __restrict__ Wi1, const float* __restrict__ Wh1,
    const float* __restrict__ cvec,
    const float* __restrict__ g0v, const float* __restrict__ be0v,
    const float* __restrict__ g1v, const float* __restrict__ be1v,
    const float* __restrict__ wfc, const float* __restrict__ bfc,
    ull* __restrict__ pay, ull* __restrict__ pst,
    ull* __restrict__ tags, float* __restrict__ out) {

  const int blk = blockIdx.x, group = blk >> 4, p = blk & 15;
  const int tid = threadIdx.x;
  const int wave = tid >> 6, lane = tid & 63;
  const int quad = lane >> 4, m16 = lane & 15;

  // row stride 536 bf16 = 268 words: 16B-aligned rows, banks spread (268%32=12)
  __shared__ unsigned short a0bf[16][536];   // bf16 v2_0^{s-1} (rows 8..15 = 0)
  __shared__ unsigned short a1bf[16][536];   // bf16 v2_1^{s-2}
  __shared__ unsigned short xsb[16][72];     // bf16 x_s (rewritten after b1)
  __shared__ float partsA[8][8][33];         // v2_0^{s-1} @ (g0.*Wh0)
  __shared__ float partsB[8][8][33];         // v2_1^{s-2} @ (g1.*Wh1)
  __shared__ float partsC[8][8][33];         // v2_0^{s-1} @ (g0.*Wi1)
  __shared__ float partsX[2][8][33];         // x_s @ Wi0 (waves 0,1)
  __shared__ float2 st0[NCH][NBLK];          // (S,Q) of v2_0^{s-1} per publisher
  __shared__ float2 st1[NCH][NBLK];          // (S,Q) of v2_1^{s-2}

  // ---------------- init ----------------
  for (int i = tid; i < 16 * 536; i += 512) {
    (&a0bf[0][0])[i] = 0; (&a1bf[0][0])[i] = 0;
  }
  for (int i = tid; i < 16 * 72; i += 512) (&xsb[0][0])[i] = 0;
  if (tid < NCH * NBLK) {
    (&st0[0][0])[tid] = make_float2(0.f, 0.f);
    (&st1[0][0])[tid] = make_float2(0.f, 0.f);
  }
  { // x_0: thread (wave=chain, lane=d)
    float xv = x[((size_t)(group * NCH + wave) * T_SZ) * DD + lane];
    xsb[wave][lane] = f2b(xv);
  }

  // ---------------- static weight B-fragments (bf16, gamma-folded) --------
  short8 wf0[2][2], wfA[2][2], wfB[2][2], wfx[2];
#pragma unroll
  for (int n = 0; n < 2; ++n)
#pragma unroll
    for (int j = 0; j < 8; ++j) wfx[n][j] = 0;
#pragma unroll
  for (int sl = 0; sl < 2; ++sl)
#pragma unroll
    for (int n = 0; n < 2; ++n) {
      const int col = p * 32 + n * 16 + m16;
#pragma unroll
      for (int j = 0; j < 8; ++j) {
        const int k = wave * 64 + sl * 32 + quad * 8 + j;
        wf0[sl][n][j] = (short)f2b(g0v[k] * Wh0[(size_t)k * HH + col]);
        wfA[sl][n][j] = (short)f2b(g0v[k] * Wi1[(size_t)k * HH + col]);
        wfB[sl][n][j] = (short)f2b(g1v[k] * Wh1[(size_t)k * HH + col]);
      }
    }
  if (wave < 2) {
#pragma unroll
    for (int n = 0; n < 2; ++n) {
      const int col = p * 32 + n * 16 + m16;
#pragma unroll
      for (int j = 0; j < 8; ++j)
        wfx[n][j] = (short)f2b(Wi0[(size_t)(wave * 32 + quad * 8 + j) * HH + col]);
    }
  }

  // epilogue constants — loaded by ALL threads (both wave halves need them)
  const int cl    = lane & 31;
  const int ech   = ((wave & 3) << 1) + (lane >> 5);   // chain 0..7 in each half
  const int col_e = p * 32 + cl;
  const float c0f = cvec[col_e],          c0i = cvec[HH + col_e];
  const float c1f = cvec[2 * HH + col_e], c1i = cvec[3 * HH + col_e];
  const float uw0 = cvec[4 * HH + col_e], uw1 = cvec[5 * HH + col_e];
  const float uh1 = cvec[6 * HH + col_e];
  const float g0c = g0v[col_e], be0c = be0v[col_e];
  const float g1c = g1v[col_e], be1c = be1v[col_e];

  // publish addresses (this thread's layer half), both parities
  const int Lp = (wave >= 4) ? 1 : 0;
  ull* const pubpay0 = pay + ((((size_t)blk * 2 + Lp) * 2 + 0) * NCH + ech) * 8 + (cl >> 2);
  ull* const pubpay1 = pubpay0 + (size_t)NCH * 8;
  ull* const pubpst0 = pst + (((size_t)blk * 2 + Lp) * 2 + 0) * NCH + ech;
  ull* const pubpst1 = pubpst0 + NCH;
  unsigned short* const ep_lds = &((wave < 4) ? a0bf : a1bf)[ech][p * 32 + cl];
  ull* const mytag = tags + blk * 8 + wave;

  // gather peer assignment: wave w handles peer-slots j0=2w (and j0+1 if <15)
  const int j0   = 2 * wave;
  const bool two = (j0 + 1 < 15);
  const int pg0  = j0 + (j0 >= p);
  const int pg1  = two ? ((j0 + 1) + ((j0 + 1) >= p)) : pg0;

  // poll plan: lanes 0..7 check peer pg0's 8 wave-tags, lanes 8..15 pg1's.
  const bool pollact = (lane < 8) || (two && lane < 16);
  const int  pwidx   = lane & 7;
  const int  ppl     = (lane < 8) ? pg0 : pg1;
  const ull* tagaddr = tags + (size_t)(group * NBLK + ppl) * 8 + pwidx;

  // -------- precomputed gather plan (both parities; statically indexed) ----
  // per-peer item space (144): [0,64)=L0 pay, [64,72)=L0 st,
  // [72,136)=L1 pay, [136,144)=L1 st.
  const ull* gp0[5]; const ull* gp1[5]; ull* glw[5]; bool gv[5], gva0[5];
#pragma unroll
  for (int k = 0; k < 5; ++k) {
    const int li  = lane + (k << 6);
    const int lim = two ? 288 : 144;
    const int jr  = (li >= 144) ? 1 : 0;
    const int r2  = li - 144 * jr;
    const int pl  = jr ? pg1 : pg0;
    gv[k]   = (li < lim);
    gva0[k] = gv[k] && (r2 < 72);        // at s==0 only the L0 half exists
    const int L  = (r2 >= 72) ? 1 : 0;
    const int rr = r2 - 72 * L;
    const size_t pb = ((size_t)(group * NBLK + pl) * 2 + L) * 2;   // + par
    if (rr < 64) {
      gp0[k] = pay + ((pb + 0) * NCH + (rr >> 3)) * 8 + (rr & 7);
      gp1[k] = pay + ((pb + 1) * NCH + (rr >> 3)) * 8 + (rr & 7);
      glw[k] = (ull*)&(L ? a1bf : a0bf)[rr >> 3][pl * 32 + 4 * (rr & 7)];
    } else {
      gp0[k] = pst + ((pb + 0) * NCH + (rr - 64));
      gp1[k] = pst + ((pb + 1) * NCH + (rr - 64));
      glw[k] = (ull*)&(L ? st1 : st0)[rr - 64][pl];   // float2 = 8B, same bits
    }
  }

  const float* xptr = x + ((size_t)(group * NCH + wave) * T_SZ + 1) * DD + lane;

  float v2prev0 = 0.f, v2prev1 = 0.f;
  __syncthreads();

  for (int s = 0; s <= T_SZ; ++s) {
    const int par = s & 1;

    // ---- hoisted LN stats (st0/st1 sealed by prev b3, stable till gather) --
    float m0 = 0.f, r0 = 0.f, m1p = 0.f, r1p = 0.f;
    if (s > 0) {
      float S = 0.f, Q = 0.f;
#pragma unroll
      for (int i = 0; i < NBLK; ++i) { float2 sq = st0[ech][i]; S += sq.x; Q += sq.y; }
      m0 = S * (1.f / HH);
      r0 = __builtin_amdgcn_rsqf(Q * (1.f / HH) - m0 * m0 + 1e-5f);
    }
    if (wave >= 4 && s > 1) {
      float S = 0.f, Q = 0.f;
#pragma unroll
      for (int i = 0; i < NBLK; ++i) { float2 sq = st1[ech][i]; S += sq.x; Q += sq.y; }
      m1p = S * (1.f / HH);
      r1p = __builtin_amdgcn_rsqf(Q * (1.f / HH) - m1p * m1p + 1e-5f);
    }

    // ================= phase 1 : ALL MFMAs (operands from slot s-1) ========
    {
      f32x4 aA0 = {0.f,0.f,0.f,0.f}, aA1 = {0.f,0.f,0.f,0.f};
      f32x4 aB0 = {0.f,0.f,0.f,0.f}, aB1 = {0.f,0.f,0.f,0.f};
      f32x4 aC0 = {0.f,0.f,0.f,0.f}, aC1 = {0.f,0.f,0.f,0.f};
#pragma unroll
      for (int sl = 0; sl < 2; ++sl) {
        const short8 af0 = *(const short8*)&a0bf[m16][wave * 64 + sl * 32 + quad * 8];
        const short8 af1 = *(const short8*)&a1bf[m16][wave * 64 + sl * 32 + quad * 8];
        aA0 = __builtin_amdgcn_mfma_f32_16x16x32_bf16(af0, wf0[sl][0], aA0, 0, 0, 0);
        aA1 = __builtin_amdgcn_mfma_f32_16x16x32_bf16(af0, wf0[sl][1], aA1, 0, 0, 0);
        aC0 = __builtin_amdgcn_mfma_f32_16x16x32_bf16(af0, wfA[sl][0], aC0, 0, 0, 0);
        aC1 = __builtin_amdgcn_mfma_f32_16x16x32_bf16(af0, wfA[sl][1], aC1, 0, 0, 0);
        aB0 = __builtin_amdgcn_mfma_f32_16x16x32_bf16(af1, wfB[sl][0], aB0, 0, 0, 0);
        aB1 = __builtin_amdgcn_mfma_f32_16x16x32_bf16(af1, wfB[sl][1], aB1, 0, 0, 0);
      }
      if (lane < 32) {
#pragma unroll
        for (int r = 0; r < 4; ++r) {
          partsA[wave][quad * 4 + r][m16]      = aA0[r];
          partsA[wave][quad * 4 + r][16 + m16] = aA1[r];
          partsB[wave][quad * 4 + r][m16]      = aB0[r];
          partsB[wave][quad * 4 + r][16 + m16] = aB1[r];
          partsC[wave][quad * 4 + r][m16]      = aC0[r];
          partsC[wave][quad * 4 + r][16 + m16] = aC1[r];
        }
      }
      if (wave < 2) {
        f32x4 ax0 = {0.f,0.f,0.f,0.f}, ax1 = {0.f,0.f,0.f,0.f};
        const short8 xf = *(const short8*)&xsb[m16][wave * 32 + quad * 8];
        ax0 = __builtin_amdgcn_mfma_f32_16x16x32_bf16(xf, wfx[0], ax0, 0, 0, 0);
        ax1 = __builtin_amdgcn_mfma_f32_16x16x32_bf16(xf, wfx[1], ax1, 0, 0, 0);
        if (lane < 32) {
#pragma unroll
          for (int r = 0; r < 4; ++r) {
            partsX[wave][quad * 4 + r][m16]      = ax0[r];
            partsX[wave][quad * 4 + r][16 + m16] = ax1[r];
          }
        }
      }
    }
    __syncthreads();                                    // b1

    // ===== parallel epilogues: waves 0-3 = L0 step s | waves 4-7 = L1 step s-1
    if (wave < 4) {
      if (s < T_SZ) {
        float sH = 0.f;
#pragma unroll
        for (int w = 0; w < 8; ++w) sH += partsA[w][ech][cl];
        const float sX = partsX[0][ech][cl] + partsX[1][ech][cl];
        const float z = ((s == 0) ? c0i : c0f) + r0 * sH - r0 * m0 * uw0 + sX;
        const float h0prev = (s == 0) ? 0.f : (v2prev0 - m0) * r0 * g0c + be0c;
        const float v2 = fast_tanh(z) + h0prev;
        v2prev0 = v2;
        const unsigned vb = f2b(v2);
        *ep_lds = (unsigned short)vb;
        const unsigned u01 = vb | (__shfl_down(vb, 1) << 16);
        const unsigned u23 = __shfl_down(u01, 2);
        if ((cl & 3) == 0)
          st_rlx((par ? pubpay1 : pubpay0), (ull)u01 | ((ull)u23 << 32));
        float S = v2, Q = v2 * v2;
#pragma unroll
        for (int off = 16; off; off >>= 1) {
          S += __shfl_down(S, off, 32); Q += __shfl_down(Q, off, 32);
        }
        if (cl == 0) {
          st0[ech][p] = make_float2(S, Q);   // safe: all st0 reads hoisted pre-b1
          st_rlx((par ? pubpst1 : pubpst0), packf2(S, Q));
        }
      }
    } else if (s >= 1) {
      float sB = 0.f, sC = 0.f;
#pragma unroll
      for (int w = 0; w < 8; ++w) { sB += partsB[w][ech][cl]; sC += partsC[w][ech][cl]; }
      const float z = ((s == 1) ? c1i : c1f) + r0 * sC - r0 * m0 * uw1
                      + r1p * sB - r1p * m1p * uh1;
      const float h1prev = (s == 1) ? 0.f : (v2prev1 - m1p) * r1p * g1c + be1c;
      const float v2 = fast_tanh(z) + h1prev;
      v2prev1 = v2;
      const unsigned vb = f2b(v2);
      *ep_lds = (unsigned short)vb;
      const unsigned u01 = vb | (__shfl_down(vb, 1) << 16);
      const unsigned u23 = __shfl_down(u01, 2);
      if ((cl & 3) == 0)
        st_rlx((par ? pubpay1 : pubpay0), (ull)u01 | ((ull)u23 << 32));
      float S = v2, Q = v2 * v2;
#pragma unroll
      for (int off = 16; off; off >>= 1) {
        S += __shfl_down(S, off, 32); Q += __shfl_down(Q, off, 32);
      }
      if (cl == 0) {
        st1[ech][p] = make_float2(S, Q);
        st_rlx((par ? pubpst1 : pubpst0), packf2(S, Q));
      }
    }

    // ---- per-wave drain-and-tag: own stores durable, then announce --------
    asm volatile("s_waitcnt vmcnt(0)" ::: "memory");
    if (lane == 0) st_rlx(mytag, (ull)(s + 1));
    if (s == T_SZ) break;

    // x prefetch issue (consumed after b3 barrier next slot)
    float xv = 0.f;
    if (s + 1 < T_SZ) xv = *xptr;
    xptr += DD;

    // -------- per-wave rendezvous: poll 2 peers' tag-lines (16 lanes) ------
    {
      const ull target = (ull)(s + 1);
      const bool mycheck = pollact && !((s == 0) && (pwidx >= 4));
      for (;;) {
        bool ok = !mycheck || (ld_rlx(tagaddr) >= target);
        if (__all(ok)) break;
        __builtin_amdgcn_s_sleep(1);
      }
    }

    // -------- register-staged gather: 5 loads then 5 LDS stores ------------
    {
      ull tv[5];
#pragma unroll
      for (int k = 0; k < 5; ++k) {
        const bool v = s ? gv[k] : gva0[k];
        tv[k] = 0;
        if (v) tv[k] = ld_rlx(par ? gp1[k] : gp0[k]);
      }
#pragma unroll
      for (int k = 0; k < 5; ++k) {
        const bool v = s ? gv[k] : gva0[k];
        if (v) *glw[k] = tv[k];
      }
    }
    if (s + 1 < T_SZ) xsb[wave][lane] = f2b(xv);
    __syncthreads();                                    // b3
  }

  // ============ head (p==0 blocks): out = LN(v2_1^{T-1}).Wfc + bfc ========
  // v2_1^{T-1} published at slot T (par=0); peers' waves 4-7 tag T+1 after
  // their drains, so payload is durable once tags observed.
  if (p == 0) {
    if (tid < 60) {
      const int pl = 1 + (tid >> 2), w = 4 + (tid & 3);
      const ull* a = tags + (size_t)(group * NBLK + pl) * 8 + w;
      while (ld_rlx(a) < (ull)(T_SZ + 1)) __builtin_amdgcn_s_sleep(2);
    }
    __syncthreads();
    const int c = wave;   // wave handles chain c
    ull su = 0;
    if (lane < 16)
      su = ld_rlx(pst + (((size_t)(group * NBLK + lane) * 2 + 1) * 2 + 0) * NCH + c);
    float S = unpack_lo(su), Q = unpack_hi(su);
#pragma unroll
    for (int off = 32; off; off >>= 1) { S += __shfl_down(S, off); Q += __shfl_down(Q, off); }
    S = __shfl(S, 0); Q = __shfl(Q, 0);
    const float m1 = S * (1.f / HH);
    const float r1 = __builtin_amdgcn_rsqf(Q * (1.f / HH) - m1 * m1 + 1e-5f);
    float o = 0.f;
#pragma unroll
    for (int it = 0; it < 2; ++it) {
      const int j2 = lane * 2 + it, pl = j2 >> 3, j = j2 & 7;
      ull u = ld_rlx(pay + ((((size_t)(group * NBLK + pl) * 2 + 1) * 2 + 0) * NCH + c) * 8 + j);
#pragma unroll
      for (int q = 0; q < 4; ++q) {
        const int col = pl * 32 + 4 * j + q;
        const float h = (b2f((unsigned short)(u >> (16 * q))) - m1) * r1 * g1v[col] + be1v[col];
        o += h * wfc[col];
      }
    }
#pragma unroll
    for (int off = 32; off; off >>= 1) o += __shfl_down(o, off);
    if (lane == 0) out[group * NCH + c] = o + bfc[0];
  }
}

extern "C" void kernel_launch(void* const* d_in, const int* in_sizes, int n_in,
                              void* d_out, int out_size, void* d_ws, size_t ws_size,
                              hipStream_t stream) {
  const float* x   = (const float*)d_in[0];
  const float* Wi0 = (const float*)d_in[1];
  const float* bi0 = (const float*)d_in[2];
  const float* Wh0 = (const float*)d_in[3];
  const float* bh0 = (const float*)d_in[4];
  const float* g0  = (const float*)d_in[5];
  const float* be0 = (const float*)d_in[6];
  const float* Wi1 = (const float*)d_in[7];
  const float* bi1 = (const float*)d_in[8];
  const float* Wh1 = (const float*)d_in[9];
  const float* bh1 = (const float*)d_in[10];
  const float* g1  = (const float*)d_in[11];
  const float* be1 = (const float*)d_in[12];
  const float* Wfc = (const float*)d_in[13];
  const float* bfc = (const float*)d_in[14];
  float* out = (float*)d_out;

  // ws: cvec 16KB | pay 512KB | pst 64KB | tags 16KB
  char* ws = (char*)d_ws;
  float* cvec = (float*)(ws);
  ull* pay    = (ull*)(ws + 16384);
  ull* pst    = (ull*)(ws + 16384 + 524288);
  ull* tags   = (ull*)(ws + 16384 + 524288 + 65536);

  prep_kernel<<<256, 256, 0, stream>>>(Wh0, Wi1, Wh1, bi0, bh0, bi1, bh1,
                                       g0, be0, g1, be1, cvec, tags);
  rnn_mfma<<<256, 512, 0, stream>>>(x, Wi0, Wh0, Wi1, Wh1, cvec,
                                    g0, be0, g1, be1, Wfc, bfc,
                                    pay, pst, tags, out);
}